// Round 3
// baseline (1624.566 us; speedup 1.0000x reference)
//
#include <hip/hip_runtime.h>
#include <stdint.h>

typedef short short8 __attribute__((ext_vector_type(8)));
typedef float f32x4 __attribute__((ext_vector_type(4)));
typedef unsigned short u16;

#define T_TOK 8192
#define HID   2048
#define FFNW  1024
#define NE    8
#define NPAIR (2 * T_TOK)

// deep-pipeline GEMM geometry
#define SLOT_U 24576   // (256 + 128) * 64 ushorts per LDS slot
#define BOFF_U 16384   // 256*64 ushorts: B region starts here within a slot

#define BAR() asm volatile("s_barrier" ::: "memory")
#define VMCNT(n) asm volatile("s_waitcnt vmcnt(" #n ")" ::: "memory")
#define PRIO(n) __builtin_amdgcn_s_setprio(n)

__device__ __forceinline__ unsigned short f2bf(float f) {
  unsigned int b = __float_as_uint(f);
  b += 0x7fffu + ((b >> 16) & 1u);   // RNE
  return (unsigned short)(b >> 16);
}
__device__ __forceinline__ float bf2f(unsigned short u) {
  return __uint_as_float(((unsigned)u) << 16);
}

#define GLOAD16(gptr, lptr)                                                          \
  __builtin_amdgcn_global_load_lds(                                                  \
      (const __attribute__((address_space(1))) unsigned int*)(gptr),                 \
      (__attribute__((address_space(3))) unsigned int*)(lptr), 16, 0, 0)

// ---------------- cast f32 -> bf16 (8 elems/thread) ----------------
__global__ __launch_bounds__(256) void k_cast(const float* __restrict__ in,
                                              unsigned short* __restrict__ out,
                                              long n8) {
  long i = (long)blockIdx.x * blockDim.x + threadIdx.x;
  long stride = (long)gridDim.x * blockDim.x;
  for (; i < n8; i += stride) {
    const float4* p = (const float4*)(in + i * 8);
    float4 a = p[0], b = p[1];
    uint4 o;
    o.x = (unsigned)f2bf(a.x) | ((unsigned)f2bf(a.y) << 16);
    o.y = (unsigned)f2bf(a.z) | ((unsigned)f2bf(a.w) << 16);
    o.z = (unsigned)f2bf(b.x) | ((unsigned)f2bf(b.y) << 16);
    o.w = (unsigned)f2bf(b.z) | ((unsigned)f2bf(b.w) << 16);
    ((uint4*)out)[i] = o;
  }
}

__global__ void k_init(int* counts) {
  if (threadIdx.x < NE) counts[threadIdx.x] = 0;
}

// ---------------- router: wave per token ----------------
__global__ __launch_bounds__(256) void k_router(const float* __restrict__ x,
                                                const float* __restrict__ gw,
                                                float* __restrict__ logits,
                                                int* __restrict__ sel,
                                                float* __restrict__ cw,
                                                int* __restrict__ counts) {
  int wid = threadIdx.x >> 6, lane = threadIdx.x & 63;
  int t = blockIdx.x * 4 + wid;
  const float4* xr = (const float4*)(x + (size_t)t * HID);
  float acc[NE];
#pragma unroll
  for (int e = 0; e < NE; e++) acc[e] = 0.f;
  for (int i = lane; i < HID / 4; i += 64) {
    float4 xv = xr[i];
#pragma unroll
    for (int e = 0; e < NE; e++) {
      float4 gv = ((const float4*)(gw + (size_t)e * HID))[i];
      acc[e] += xv.x * gv.x + xv.y * gv.y + xv.z * gv.z + xv.w * gv.w;
    }
  }
#pragma unroll
  for (int e = 0; e < NE; e++)
    for (int off = 32; off; off >>= 1) acc[e] += __shfl_down(acc[e], off);
  if (lane == 0) {
    float mx = acc[0];
#pragma unroll
    for (int e = 1; e < NE; e++) mx = fmaxf(mx, acc[e]);
    float p[NE];
#pragma unroll
    for (int e = 0; e < NE; e++) p[e] = expf(acc[e] - mx);
    int i1 = 0; float b1 = p[0];
#pragma unroll
    for (int e = 1; e < NE; e++) if (p[e] > b1) { b1 = p[e]; i1 = e; }
    int i2 = -1; float b2 = -1.f;
#pragma unroll
    for (int e = 0; e < NE; e++) if (e != i1 && p[e] > b2) { b2 = p[e]; i2 = e; }
    float denom = b1 + b2;
#pragma unroll
    for (int e = 0; e < NE; e++) logits[(size_t)t * NE + e] = acc[e];
    sel[2 * t] = i1; sel[2 * t + 1] = i2;
    cw[2 * t] = b1 / denom; cw[2 * t + 1] = b2 / denom;
    atomicAdd(&counts[i1], 1);
    atomicAdd(&counts[i2], 1);
  }
}

__global__ void k_offsets(const int* __restrict__ counts, int* __restrict__ base,
                          int* __restrict__ cursor) {
  if (threadIdx.x == 0 && blockIdx.x == 0) {
    int acc = 0;
    for (int e = 0; e < NE; e++) { base[e] = acc; cursor[e] = acc; acc += counts[e]; }
    base[NE] = acc;
  }
}

__global__ __launch_bounds__(256) void k_scatter(const int* __restrict__ sel,
                                                 int* __restrict__ cursor,
                                                 int* __restrict__ tokc,
                                                 int* __restrict__ inv) {
  int t = blockIdx.x * blockDim.x + threadIdx.x;
  if (t >= T_TOK) return;
#pragma unroll
  for (int k = 0; k < 2; k++) {
    int e = sel[2 * t + k];
    int pos = atomicAdd(&cursor[e], 1);
    tokc[pos] = t;
    inv[2 * t + k] = pos;
  }
}

// ---------------- deep-pipelined 256x128x64 MFMA GEMM ----------------
// 8 waves (4M x 2N), 3-slot LDS (144 KiB), counted vmcnt pipeline:
//   prologue: stage T0,T1,T2; vmcnt(12) -> T0 landed (2 tiles = 12 loads in flight)
//   iter t: [phaseA 16 MFMA][phaseB 16 MFMA] ... vmcnt(6) -> T_{t+1} landed; barrier;
//           issue T_{t+3} into slot t%3 (all waves provably done reading it).
// XOR chunk-swizzle (chunk ^ row&7): zero bank conflicts (verified round 2).
template<bool GATHER, int KD, int ND>
__global__ __launch_bounds__(512, 2) void k_gemm_dp(const u16* __restrict__ A,
                                                    const u16* __restrict__ W,
                                                    u16* __restrict__ Y,
                                                    const int* __restrict__ counts,
                                                    const int* __restrict__ base_,
                                                    const int* __restrict__ tokc) {
  int e = blockIdx.z;
  int cnt = counts[e];
  int m0 = blockIdx.x * 256;
  if (m0 >= cnt) return;
  int n0 = blockIdx.y * 128;
  int bs = base_[e];

  __shared__ u16 lds[3 * SLOT_U];
  __shared__ int s_row[256];

  int tid = threadIdx.x;
  if (tid < 256) {
    int sl = m0 + tid;
    int cl = sl < cnt ? sl : 0;
    s_row[tid] = GATHER ? tokc[bs + cl] : (bs + cl);
  }
  __syncthreads();

  int wid = tid >> 6, lane = tid & 63;
  int l3 = lane >> 3, l7 = lane & 7;
  int cs = l7 ^ l3;  // pre-swizzled 16B-chunk of the global source

  const u16* wb = W + (size_t)e * ND * KD;

  size_t aoff[4]; unsigned abase[4];
  size_t boff[2]; unsigned bbase[2];
#pragma unroll
  for (int i = 0; i < 4; i++) {
    int grow = i * 64 + wid * 8 + l3;
    aoff[i] = (size_t)s_row[grow] * KD + (size_t)cs * 8;
    abase[i] = (unsigned)((i * 64 + wid * 8) * 64);
  }
#pragma unroll
  for (int j = 0; j < 2; j++) {
    int brow = j * 64 + wid * 8 + l3;
    boff[j] = (size_t)(n0 + brow) * KD + (size_t)cs * 8;
    bbase[j] = (unsigned)(BOFF_U + (j * 64 + wid * 8) * 64);
  }

  f32x4 acc[4][4];
#pragma unroll
  for (int mi = 0; mi < 4; mi++)
#pragma unroll
    for (int ni = 0; ni < 4; ni++) acc[mi][ni] = (f32x4)(0.f);

  int wrow = (wid >> 1) * 64, wcol = (wid & 1) * 64;
  int frow = lane & 15, fk = lane >> 4;

  constexpr int NT = KD / 64;

  auto STAGE = [&](int u) {
    unsigned so = (unsigned)(u % 3) * SLOT_U;
    size_t ko = (size_t)u * 64;
#pragma unroll
    for (int i = 0; i < 4; i++) GLOAD16(A + aoff[i] + ko, &lds[so + abase[i]]);
#pragma unroll
    for (int j = 0; j < 2; j++) GLOAD16(wb + boff[j] + ko, &lds[so + bbase[j]]);
  };

  STAGE(0); STAGE(1); STAGE(2);
  VMCNT(12);
  BAR();

  for (int t = 0; t < NT; ++t) {
    const char* sb = (const char*)lds + (size_t)(t % 3) * (SLOT_U * 2);

    // ---- phase A: all B frags + A frags mi=0,1; 16 MFMA ----
    short8 bf[4][2], af[2][2];
#pragma unroll
    for (int ni = 0; ni < 4; ni++)
#pragma unroll
      for (int kk = 0; kk < 2; kk++)
        bf[ni][kk] = *(const short8*)(sb + BOFF_U * 2 + (wcol + ni * 16 + frow) * 128 +
                                      (((fk + kk * 4) ^ l7) << 4));
#pragma unroll
    for (int mi = 0; mi < 2; mi++)
#pragma unroll
      for (int kk = 0; kk < 2; kk++)
        af[mi][kk] = *(const short8*)(sb + (wrow + mi * 16 + frow) * 128 +
                                      (((fk + kk * 4) ^ l7) << 4));
    BAR();
    PRIO(1);
#pragma unroll
    for (int mi = 0; mi < 2; mi++)
#pragma unroll
      for (int ni = 0; ni < 4; ni++)
#pragma unroll
        for (int kk = 0; kk < 2; kk++)
          acc[mi][ni] = __builtin_amdgcn_mfma_f32_16x16x32_bf16(af[mi][kk], bf[ni][kk],
                                                                acc[mi][ni], 0, 0, 0);
    PRIO(0);
    BAR();

    // ---- phase B: A frags mi=2,3; 16 MFMA ----
    short8 af2[2][2];
#pragma unroll
    for (int mi = 0; mi < 2; mi++)
#pragma unroll
      for (int kk = 0; kk < 2; kk++)
        af2[mi][kk] = *(const short8*)(sb + (wrow + (mi + 2) * 16 + frow) * 128 +
                                       (((fk + kk * 4) ^ l7) << 4));
    BAR();
    PRIO(1);
#pragma unroll
    for (int mi = 0; mi < 2; mi++)
#pragma unroll
      for (int ni = 0; ni < 4; ni++)
#pragma unroll
        for (int kk = 0; kk < 2; kk++)
          acc[mi + 2][ni] = __builtin_amdgcn_mfma_f32_16x16x32_bf16(af2[mi][kk], bf[ni][kk],
                                                                    acc[mi + 2][ni], 0, 0, 0);
    PRIO(0);
    // counted drain: T_{t+1} must be fully landed for everyone after the barrier.
    if (t == NT - 2) { VMCNT(0); } else { VMCNT(6); }
    BAR();
    if (t + 3 < NT) STAGE(t + 3);
  }

  // epilogue: C/D layout col=lane&15, row=(lane>>4)*4+r
#pragma unroll
  for (int mi = 0; mi < 4; mi++) {
#pragma unroll
    for (int r = 0; r < 4; r++) {
      int row = wrow + mi * 16 + fk * 4 + r;
      int sl = m0 + row;
      if (sl < cnt) {
        u16* yr = Y + (size_t)(bs + sl) * ND + n0 + wcol + frow;
#pragma unroll
        for (int ni = 0; ni < 4; ni++) yr[ni * 16] = f2bf(acc[mi][ni][r]);
      }
    }
  }
}

// ---------------- SwiGLU: act = silu(g) * u ----------------
__global__ __launch_bounds__(256) void k_swiglu(const unsigned short* __restrict__ h13,
                                                unsigned short* __restrict__ act) {
  long i = (long)blockIdx.x * 256 + threadIdx.x;
  int p = (int)(i >> 7);
  int c = (int)(i & 127);
  const unsigned short* hr = h13 + (size_t)p * (2 * FFNW);
  short8 g8 = *(const short8*)(hr + c * 8);
  short8 u8 = *(const short8*)(hr + FFNW + c * 8);
  short8 o;
#pragma unroll
  for (int j = 0; j < 8; j++) {
    float g = bf2f((unsigned short)g8[j]);
    float u = bf2f((unsigned short)u8[j]);
    float sv = g / (1.f + expf(-g));
    o[j] = (short)f2bf(sv * u);
  }
  *(short8*)(act + (size_t)p * FFNW + c * 8) = o;
}

// ---------------- combine: out[t] = c0*y[p0] + c1*y[p1] ----------------
__global__ __launch_bounds__(256) void k_combine(const unsigned short* __restrict__ y,
                                                 const int* __restrict__ inv,
                                                 const float* __restrict__ cw,
                                                 float* __restrict__ out) {
  long i = (long)blockIdx.x * 256 + threadIdx.x;
  int t = (int)(i >> 8);
  int c = (int)(i & 255);
  int p0 = inv[2 * t], p1 = inv[2 * t + 1];
  float c0 = cw[2 * t], c1 = cw[2 * t + 1];
  short8 y0 = *(const short8*)(y + (size_t)p0 * HID + c * 8);
  short8 y1 = *(const short8*)(y + (size_t)p1 * HID + c * 8);
  float4 o0, o1;
  o0.x = c0 * bf2f((unsigned short)y0[0]) + c1 * bf2f((unsigned short)y1[0]);
  o0.y = c0 * bf2f((unsigned short)y0[1]) + c1 * bf2f((unsigned short)y1[1]);
  o0.z = c0 * bf2f((unsigned short)y0[2]) + c1 * bf2f((unsigned short)y1[2]);
  o0.w = c0 * bf2f((unsigned short)y0[3]) + c1 * bf2f((unsigned short)y1[3]);
  o1.x = c0 * bf2f((unsigned short)y0[4]) + c1 * bf2f((unsigned short)y1[4]);
  o1.y = c0 * bf2f((unsigned short)y0[5]) + c1 * bf2f((unsigned short)y1[5]);
  o1.z = c0 * bf2f((unsigned short)y0[6]) + c1 * bf2f((unsigned short)y1[6]);
  o1.w = c0 * bf2f((unsigned short)y0[7]) + c1 * bf2f((unsigned short)y1[7]);
  float4* op = (float4*)(out + (size_t)t * HID + c * 8);
  op[0] = o0;
  op[1] = o1;
}

extern "C" void kernel_launch(void* const* d_in, const int* in_sizes, int n_in,
                              void* d_out, int out_size, void* d_ws, size_t ws_size,
                              hipStream_t stream) {
  const float* x   = (const float*)d_in[0];
  const float* gw  = (const float*)d_in[1];
  const float* w13 = (const float*)d_in[2];
  const float* w2  = (const float*)d_in[3];
  float* out = (float*)d_out;
  float* logits = out + (size_t)T_TOK * HID;

  uint8_t* p = (uint8_t*)d_ws;
  unsigned short* xb   = (unsigned short*)p; p += (size_t)T_TOK * HID * 2;
  unsigned short* w13b = (unsigned short*)p; p += (size_t)NE * 2 * FFNW * HID * 2;
  unsigned short* w2b  = (unsigned short*)p; p += (size_t)NE * HID * FFNW * 2;
  unsigned short* act  = (unsigned short*)p; p += (size_t)NPAIR * FFNW * 2;
  unsigned short* h13  = (unsigned short*)p; p += (size_t)NPAIR * 2 * FFNW * 2;
  unsigned short* y    = h13;  // y aliases h13 (h13 dead after swiglu)
  int* sel  = (int*)p;   p += (size_t)T_TOK * 2 * 4;
  float* cw = (float*)p; p += (size_t)T_TOK * 2 * 4;
  int* tokc = (int*)p;   p += (size_t)NPAIR * 4;
  int* inv  = (int*)p;   p += (size_t)NPAIR * 4;
  int* counts = (int*)p; p += 256;
  int* cursor = (int*)p; p += 256;
  int* base   = (int*)p; p += 256;
  if ((size_t)(p - (uint8_t*)d_ws) > ws_size) return;

  k_cast<<<2048, 256, 0, stream>>>(x, xb, (long)T_TOK * HID / 8);
  k_cast<<<2048, 256, 0, stream>>>(w13, w13b, (long)NE * 2 * FFNW * HID / 8);
  k_cast<<<2048, 256, 0, stream>>>(w2, w2b, (long)NE * HID * FFNW / 8);
  k_init<<<1, 64, 0, stream>>>(counts);
  k_router<<<T_TOK / 4, 256, 0, stream>>>(x, gw, logits, sel, cw, counts);
  k_offsets<<<1, 1, 0, stream>>>(counts, base, cursor);
  k_scatter<<<T_TOK / 256, 256, 0, stream>>>(sel, cursor, tokc, inv);

  // GEMM1: h13[pair][2F] = x_gathered @ w13[e]^T   (256x128 tile, deep pipeline)
  k_gemm_dp<true, HID, 2 * FFNW><<<dim3(T_TOK / 256, (2 * FFNW) / 128, NE), 512, 0, stream>>>(
      xb, w13b, h13, counts, base, tokc);
  // SwiGLU
  k_swiglu<<<(int)((long)NPAIR * FFNW / 8 / 256), 256, 0, stream>>>(h13, act);
  // GEMM2: y[pair][H] = act @ w2[e]^T
  k_gemm_dp<false, FFNW, HID><<<dim3(T_TOK / 256, HID / 128, NE), 512, 0, stream>>>(
      act, w2b, y, counts, base, tokc);
  // combine into out
  k_combine<<<(int)((long)T_TOK * HID / 8 / 256), 256, 0, stream>>>(y, inv, cw, out);
}

// Round 4
// 711.496 us; speedup vs baseline: 2.2833x; 2.2833x over previous
//
#include <hip/hip_runtime.h>
#include <stdint.h>

typedef short short8 __attribute__((ext_vector_type(8)));
typedef float f32x4 __attribute__((ext_vector_type(4)));
typedef unsigned short u16;

#define T_TOK 8192
#define HID   2048
#define FFNW  1024
#define NE    8
#define NPAIR (2 * T_TOK)

__device__ __forceinline__ unsigned short f2bf(float f) {
  unsigned int b = __float_as_uint(f);
  b += 0x7fffu + ((b >> 16) & 1u);   // RNE
  return (unsigned short)(b >> 16);
}
__device__ __forceinline__ float bf2f(unsigned short u) {
  return __uint_as_float(((unsigned)u) << 16);
}

#define GLOAD16(gptr, lptr)                                                          \
  __builtin_amdgcn_global_load_lds(                                                  \
      (const __attribute__((address_space(1))) unsigned int*)(gptr),                 \
      (__attribute__((address_space(3))) unsigned int*)(lptr), 16, 0, 0)

// ---------------- cast f32 -> bf16 (8 elems/thread) ----------------
__global__ __launch_bounds__(256) void k_cast(const float* __restrict__ in,
                                              unsigned short* __restrict__ out,
                                              long n8) {
  long i = (long)blockIdx.x * blockDim.x + threadIdx.x;
  long stride = (long)gridDim.x * blockDim.x;
  for (; i < n8; i += stride) {
    const float4* p = (const float4*)(in + i * 8);
    float4 a = p[0], b = p[1];
    uint4 o;
    o.x = (unsigned)f2bf(a.x) | ((unsigned)f2bf(a.y) << 16);
    o.y = (unsigned)f2bf(a.z) | ((unsigned)f2bf(a.w) << 16);
    o.z = (unsigned)f2bf(b.x) | ((unsigned)f2bf(b.y) << 16);
    o.w = (unsigned)f2bf(b.z) | ((unsigned)f2bf(b.w) << 16);
    ((uint4*)out)[i] = o;
  }
}

__global__ void k_init(int* counts) {
  if (threadIdx.x < NE) counts[threadIdx.x] = 0;
}

// ---------------- router: wave per token ----------------
__global__ __launch_bounds__(256) void k_router(const float* __restrict__ x,
                                                const float* __restrict__ gw,
                                                float* __restrict__ logits,
                                                int* __restrict__ sel,
                                                float* __restrict__ cw,
                                                int* __restrict__ counts) {
  int wid = threadIdx.x >> 6, lane = threadIdx.x & 63;
  int t = blockIdx.x * 4 + wid;
  const float4* xr = (const float4*)(x + (size_t)t * HID);
  float acc[NE];
#pragma unroll
  for (int e = 0; e < NE; e++) acc[e] = 0.f;
  for (int i = lane; i < HID / 4; i += 64) {
    float4 xv = xr[i];
#pragma unroll
    for (int e = 0; e < NE; e++) {
      float4 gv = ((const float4*)(gw + (size_t)e * HID))[i];
      acc[e] += xv.x * gv.x + xv.y * gv.y + xv.z * gv.z + xv.w * gv.w;
    }
  }
#pragma unroll
  for (int e = 0; e < NE; e++)
    for (int off = 32; off; off >>= 1) acc[e] += __shfl_down(acc[e], off);
  if (lane == 0) {
    float mx = acc[0];
#pragma unroll
    for (int e = 1; e < NE; e++) mx = fmaxf(mx, acc[e]);
    float p[NE];
#pragma unroll
    for (int e = 0; e < NE; e++) p[e] = expf(acc[e] - mx);
    int i1 = 0; float b1 = p[0];
#pragma unroll
    for (int e = 1; e < NE; e++) if (p[e] > b1) { b1 = p[e]; i1 = e; }
    int i2 = -1; float b2 = -1.f;
#pragma unroll
    for (int e = 0; e < NE; e++) if (e != i1 && p[e] > b2) { b2 = p[e]; i2 = e; }
    float denom = b1 + b2;
#pragma unroll
    for (int e = 0; e < NE; e++) logits[(size_t)t * NE + e] = acc[e];
    sel[2 * t] = i1; sel[2 * t + 1] = i2;
    cw[2 * t] = b1 / denom; cw[2 * t + 1] = b2 / denom;
    atomicAdd(&counts[i1], 1);
    atomicAdd(&counts[i2], 1);
  }
}

__global__ void k_offsets(const int* __restrict__ counts, int* __restrict__ base,
                          int* __restrict__ cursor) {
  if (threadIdx.x == 0 && blockIdx.x == 0) {
    int acc = 0;
    for (int e = 0; e < NE; e++) { base[e] = acc; cursor[e] = acc; acc += counts[e]; }
    base[NE] = acc;
  }
}

__global__ __launch_bounds__(256) void k_scatter(const int* __restrict__ sel,
                                                 int* __restrict__ cursor,
                                                 int* __restrict__ tokc,
                                                 int* __restrict__ inv) {
  int t = blockIdx.x * blockDim.x + threadIdx.x;
  if (t >= T_TOK) return;
#pragma unroll
  for (int k = 0; k < 2; k++) {
    int e = sel[2 * t + k];
    int pos = atomicAdd(&cursor[e], 1);
    tokc[pos] = t;
    inv[2 * t + k] = pos;
  }
}

// XCD-aware remap: linear block -> work item, expert-major chunks per XCD.
// NWG must be divisible by 8. (perf heuristic only)
__device__ __forceinline__ int xcd_remap(int L, int nwg) {
  return (L & 7) * (nwg >> 3) + (L >> 3);
}

// ============ GEMM1 fused SwiGLU: act[pair][F] = silu(x@w1^T)*(x@w3^T) ============
// 128 rows x 64 ffn-cols per block; B = w1[n0..n0+64) || w3[n0..n0+64) (128 rows).
// Min-2-phase: STAGE(t+1 -> buf^1); ds_read+MFMA from buf; __syncthreads (vmcnt0); flip.
__global__ __launch_bounds__(256) void k_g1(const u16* __restrict__ A,
                                            const u16* __restrict__ W,
                                            u16* __restrict__ act,
                                            const int* __restrict__ counts,
                                            const int* __restrict__ base_,
                                            const int* __restrict__ tokc) {
  // grid: 64 m-blocks x 16 n-blocks x 8 experts, launched 1-D (8192)
  int Wk = xcd_remap(blockIdx.x, 64 * 16 * NE);
  int bx = Wk & 63, by = (Wk >> 6) & 15, e = Wk >> 10;

  int cnt = counts[e];
  int m0 = bx * 128;
  if (m0 >= cnt) return;
  int n0 = by * 64;
  int bs = base_[e];

  __shared__ u16 lds[2][2 * 128 * 64];   // per buf: A[128][64] then B[128][64]
  __shared__ int s_row[128];

  int tid = threadIdx.x;
  if (tid < 128) {
    int sl = m0 + tid;
    s_row[tid] = tokc[bs + (sl < cnt ? sl : 0)];
  }
  __syncthreads();

  int wave = tid >> 6, lane = tid & 63;
  int l3 = lane >> 3, l7 = lane & 7;
  int cs = l7 ^ l3;  // pre-swizzled 16B chunk of global source

  const u16* wb = W + (size_t)e * (2 * FFNW) * HID;

  size_t aoff[4], boff[4];
  unsigned abase[4], bbase[4];
#pragma unroll
  for (int i = 0; i < 4; i++) {
    int lrow = i * 32 + wave * 8;
    aoff[i] = (size_t)s_row[lrow + l3] * HID + (size_t)cs * 8;
    abase[i] = (unsigned)(lrow * 64);
    int grow = (i < 2) ? (n0 + lrow + l3) : (FFNW + n0 + (lrow - 64) + l3);
    boff[i] = (size_t)grow * HID + (size_t)cs * 8;
    bbase[i] = (unsigned)(128 * 64 + lrow * 64);
  }

  f32x4 accg[4][2], accu[4][2];
#pragma unroll
  for (int mi = 0; mi < 4; mi++)
#pragma unroll
    for (int ni = 0; ni < 2; ni++) { accg[mi][ni] = (f32x4)(0.f); accu[mi][ni] = (f32x4)(0.f); }

  int wrow = (wave >> 1) * 64, wcoff = (wave & 1) * 32;
  int frow = lane & 15, fk = lane >> 4;

  constexpr int NT = HID / 64;

  auto STAGE = [&](int buf, int t) {
    size_t ko = (size_t)t * 64;
#pragma unroll
    for (int i = 0; i < 4; i++) {
      GLOAD16(A + aoff[i] + ko, &lds[buf][abase[i]]);
      GLOAD16(wb + boff[i] + ko, &lds[buf][bbase[i]]);
    }
  };

  STAGE(0, 0);
  __syncthreads();   // vmcnt(0): buf0 landed

  int cur = 0;
  for (int t = 0; t < NT; ++t) {
    if (t + 1 < NT) STAGE(cur ^ 1, t + 1);   // overlaps with compute below
    const char* sb = (const char*)lds[cur];
#pragma unroll
    for (int kk = 0; kk < 2; kk++) {
      int q = fk + kk * 4;
      short8 af[4], bg[2], bu[2];
#pragma unroll
      for (int mi = 0; mi < 4; mi++) {
        int r = wrow + mi * 16 + frow;
        af[mi] = *(const short8*)(sb + r * 128 + (((q ^ (r & 7)) << 4)));
      }
#pragma unroll
      for (int ni = 0; ni < 2; ni++) {
        int rg = wcoff + ni * 16 + frow;
        bg[ni] = *(const short8*)(sb + 128 * 128 + rg * 128 + ((q ^ (rg & 7)) << 4));
        int ru = 64 + rg;
        bu[ni] = *(const short8*)(sb + 128 * 128 + ru * 128 + ((q ^ (ru & 7)) << 4));
      }
#pragma unroll
      for (int mi = 0; mi < 4; mi++)
#pragma unroll
        for (int ni = 0; ni < 2; ni++) {
          accg[mi][ni] = __builtin_amdgcn_mfma_f32_16x16x32_bf16(af[mi], bg[ni], accg[mi][ni], 0, 0, 0);
          accu[mi][ni] = __builtin_amdgcn_mfma_f32_16x16x32_bf16(af[mi], bu[ni], accu[mi][ni], 0, 0, 0);
        }
    }
    __syncthreads();   // vmcnt(0)+lgkmcnt(0)+barrier: next buf landed, all reads done
    cur ^= 1;
  }

  // epilogue: C/D col=lane&15, row=(lane>>4)*4+r; act = silu(g)*u
#pragma unroll
  for (int mi = 0; mi < 4; mi++) {
#pragma unroll
    for (int r = 0; r < 4; r++) {
      int row = wrow + mi * 16 + fk * 4 + r;
      int sl = m0 + row;
      if (sl < cnt) {
        u16* yr = act + (size_t)(bs + sl) * FFNW + n0 + wcoff + frow;
#pragma unroll
        for (int ni = 0; ni < 2; ni++) {
          float g = accg[mi][ni][r];
          float u = accu[mi][ni][r];
          float sv = g / (1.f + expf(-g));
          yr[ni * 16] = f2bf(sv * u);
        }
      }
    }
  }
}

// ============ GEMM2: y[pair][H] = act @ w2[e]^T, 128x128 min-2-phase ============
__global__ __launch_bounds__(256) void k_g2(const u16* __restrict__ A,
                                            const u16* __restrict__ W,
                                            u16* __restrict__ Y,
                                            const int* __restrict__ counts,
                                            const int* __restrict__ base_) {
  int Wk = xcd_remap(blockIdx.x, 64 * 16 * NE);
  int bx = Wk & 63, by = (Wk >> 6) & 15, e = Wk >> 10;

  int cnt = counts[e];
  int m0 = bx * 128;
  if (m0 >= cnt) return;
  int n0 = by * 128;
  int bs = base_[e];

  __shared__ u16 lds[2][2 * 128 * 64];   // per buf: A[128][64] then B[128][64]

  int tid = threadIdx.x;
  int wave = tid >> 6, lane = tid & 63;
  int l3 = lane >> 3, l7 = lane & 7;
  int cs = l7 ^ l3;

  const u16* wb = W + (size_t)e * HID * FFNW;

  size_t aoff[4], boff[4];
  unsigned abase[4], bbase[4];
#pragma unroll
  for (int i = 0; i < 4; i++) {
    int lrow = i * 32 + wave * 8;
    int sl = m0 + lrow + l3;
    aoff[i] = (size_t)(bs + (sl < cnt ? sl : 0)) * FFNW + (size_t)cs * 8;
    abase[i] = (unsigned)(lrow * 64);
    boff[i] = (size_t)(n0 + lrow + l3) * FFNW + (size_t)cs * 8;
    bbase[i] = (unsigned)(128 * 64 + lrow * 64);
  }

  f32x4 acc[4][4];
#pragma unroll
  for (int mi = 0; mi < 4; mi++)
#pragma unroll
    for (int ni = 0; ni < 4; ni++) acc[mi][ni] = (f32x4)(0.f);

  int wrow = (wave >> 1) * 64, wcol = (wave & 1) * 64;
  int frow = lane & 15, fk = lane >> 4;

  constexpr int NT = FFNW / 64;

  auto STAGE = [&](int buf, int t) {
    size_t ko = (size_t)t * 64;
#pragma unroll
    for (int i = 0; i < 4; i++) {
      GLOAD16(A + aoff[i] + ko, &lds[buf][abase[i]]);
      GLOAD16(wb + boff[i] + ko, &lds[buf][bbase[i]]);
    }
  };

  STAGE(0, 0);
  __syncthreads();

  int cur = 0;
  for (int t = 0; t < NT; ++t) {
    if (t + 1 < NT) STAGE(cur ^ 1, t + 1);
    const char* sb = (const char*)lds[cur];
#pragma unroll
    for (int kk = 0; kk < 2; kk++) {
      int q = fk + kk * 4;
      short8 af[4], bf[4];
#pragma unroll
      for (int mi = 0; mi < 4; mi++) {
        int r = wrow + mi * 16 + frow;
        af[mi] = *(const short8*)(sb + r * 128 + ((q ^ (r & 7)) << 4));
      }
#pragma unroll
      for (int ni = 0; ni < 4; ni++) {
        int r = wcol + ni * 16 + frow;
        bf[ni] = *(const short8*)(sb + 128 * 128 + r * 128 + ((q ^ (r & 7)) << 4));
      }
#pragma unroll
      for (int mi = 0; mi < 4; mi++)
#pragma unroll
        for (int ni = 0; ni < 4; ni++)
          acc[mi][ni] = __builtin_amdgcn_mfma_f32_16x16x32_bf16(af[mi], bf[ni], acc[mi][ni], 0, 0, 0);
    }
    __syncthreads();
    cur ^= 1;
  }

#pragma unroll
  for (int mi = 0; mi < 4; mi++) {
#pragma unroll
    for (int r = 0; r < 4; r++) {
      int row = wrow + mi * 16 + fk * 4 + r;
      int sl = m0 + row;
      if (sl < cnt) {
        u16* yr = Y + (size_t)(bs + sl) * HID + n0 + wcol + frow;
#pragma unroll
        for (int ni = 0; ni < 4; ni++) yr[ni * 16] = f2bf(acc[mi][ni][r]);
      }
    }
  }
}

// ---------------- combine: out[t] = c0*y[p0] + c1*y[p1] ----------------
__global__ __launch_bounds__(256) void k_combine(const unsigned short* __restrict__ y,
                                                 const int* __restrict__ inv,
                                                 const float* __restrict__ cw,
                                                 float* __restrict__ out) {
  long i = (long)blockIdx.x * 256 + threadIdx.x;
  int t = (int)(i >> 8);
  int c = (int)(i & 255);
  int p0 = inv[2 * t], p1 = inv[2 * t + 1];
  float c0 = cw[2 * t], c1 = cw[2 * t + 1];
  short8 y0 = *(const short8*)(y + (size_t)p0 * HID + c * 8);
  short8 y1 = *(const short8*)(y + (size_t)p1 * HID + c * 8);
  float4 o0, o1;
  o0.x = c0 * bf2f((unsigned short)y0[0]) + c1 * bf2f((unsigned short)y1[0]);
  o0.y = c0 * bf2f((unsigned short)y0[1]) + c1 * bf2f((unsigned short)y1[1]);
  o0.z = c0 * bf2f((unsigned short)y0[2]) + c1 * bf2f((unsigned short)y1[2]);
  o0.w = c0 * bf2f((unsigned short)y0[3]) + c1 * bf2f((unsigned short)y1[3]);
  o1.x = c0 * bf2f((unsigned short)y0[4]) + c1 * bf2f((unsigned short)y1[4]);
  o1.y = c0 * bf2f((unsigned short)y0[5]) + c1 * bf2f((unsigned short)y1[5]);
  o1.z = c0 * bf2f((unsigned short)y0[6]) + c1 * bf2f((unsigned short)y1[6]);
  o1.w = c0 * bf2f((unsigned short)y0[7]) + c1 * bf2f((unsigned short)y1[7]);
  float4* op = (float4*)(out + (size_t)t * HID + c * 8);
  op[0] = o0;
  op[1] = o1;
}

extern "C" void kernel_launch(void* const* d_in, const int* in_sizes, int n_in,
                              void* d_out, int out_size, void* d_ws, size_t ws_size,
                              hipStream_t stream) {
  const float* x   = (const float*)d_in[0];
  const float* gw  = (const float*)d_in[1];
  const float* w13 = (const float*)d_in[2];
  const float* w2  = (const float*)d_in[3];
  float* out = (float*)d_out;
  float* logits = out + (size_t)T_TOK * HID;

  uint8_t* p = (uint8_t*)d_ws;
  unsigned short* xb   = (unsigned short*)p; p += (size_t)T_TOK * HID * 2;
  unsigned short* w13b = (unsigned short*)p; p += (size_t)NE * 2 * FFNW * HID * 2;
  unsigned short* w2b  = (unsigned short*)p; p += (size_t)NE * HID * FFNW * 2;
  unsigned short* act  = (unsigned short*)p; p += (size_t)NPAIR * FFNW * 2;
  unsigned short* y    = (unsigned short*)p; p += (size_t)NPAIR * HID * 2;
  int* sel  = (int*)p;   p += (size_t)T_TOK * 2 * 4;
  float* cw = (float*)p; p += (size_t)T_TOK * 2 * 4;
  int* tokc = (int*)p;   p += (size_t)NPAIR * 4;
  int* inv  = (int*)p;   p += (size_t)NPAIR * 4;
  int* counts = (int*)p; p += 256;
  int* cursor = (int*)p; p += 256;
  int* base   = (int*)p; p += 256;
  if ((size_t)(p - (uint8_t*)d_ws) > ws_size) return;

  k_cast<<<2048, 256, 0, stream>>>(x, xb, (long)T_TOK * HID / 8);
  k_cast<<<2048, 256, 0, stream>>>(w13, w13b, (long)NE * 2 * FFNW * HID / 8);
  k_cast<<<2048, 256, 0, stream>>>(w2, w2b, (long)NE * HID * FFNW / 8);
  k_init<<<1, 64, 0, stream>>>(counts);
  k_router<<<T_TOK / 4, 256, 0, stream>>>(x, gw, logits, sel, cw, counts);
  k_offsets<<<1, 1, 0, stream>>>(counts, base, cursor);
  k_scatter<<<T_TOK / 256, 256, 0, stream>>>(sel, cursor, tokc, inv);

  // GEMM1 + fused SwiGLU: act[pair][F]
  k_g1<<<64 * 16 * NE, 256, 0, stream>>>(xb, w13b, act, counts, base, tokc);
  // GEMM2: y[pair][H]
  k_g2<<<64 * 16 * NE, 256, 0, stream>>>(act, w2b, y, counts, base);
  // combine into out
  k_combine<<<(int)((long)T_TOK * HID / 8 / 256), 256, 0, stream>>>(y, inv, cw, out);
}

// Round 5
// 636.531 us; speedup vs baseline: 2.5522x; 1.1178x over previous
//
#include <hip/hip_runtime.h>
#include <stdint.h>

typedef short short8 __attribute__((ext_vector_type(8)));
typedef float f32x4 __attribute__((ext_vector_type(4)));
typedef unsigned short u16;

#define T_TOK 8192
#define HID   2048
#define FFNW  1024
#define NE    8
#define NPAIR (2 * T_TOK)

__device__ __forceinline__ unsigned short f2bf(float f) {
  unsigned int b = __float_as_uint(f);
  b += 0x7fffu + ((b >> 16) & 1u);   // RNE
  return (unsigned short)(b >> 16);
}
__device__ __forceinline__ float bf2f(unsigned short u) {
  return __uint_as_float(((unsigned)u) << 16);
}

#define GLOAD16(gptr, lptr)                                                          \
  __builtin_amdgcn_global_load_lds(                                                  \
      (const __attribute__((address_space(1))) unsigned int*)(gptr),                 \
      (__attribute__((address_space(3))) unsigned int*)(lptr), 16, 0, 0)

// ---------------- cast f32 -> bf16 (8 elems/thread) ----------------
__global__ __launch_bounds__(256) void k_cast(const float* __restrict__ in,
                                              unsigned short* __restrict__ out,
                                              long n8) {
  long i = (long)blockIdx.x * blockDim.x + threadIdx.x;
  long stride = (long)gridDim.x * blockDim.x;
  for (; i < n8; i += stride) {
    const float4* p = (const float4*)(in + i * 8);
    float4 a = p[0], b = p[1];
    uint4 o;
    o.x = (unsigned)f2bf(a.x) | ((unsigned)f2bf(a.y) << 16);
    o.y = (unsigned)f2bf(a.z) | ((unsigned)f2bf(a.w) << 16);
    o.z = (unsigned)f2bf(b.x) | ((unsigned)f2bf(b.y) << 16);
    o.w = (unsigned)f2bf(b.z) | ((unsigned)f2bf(b.w) << 16);
    ((uint4*)out)[i] = o;
  }
}

__global__ void k_init(int* counts) {
  if (threadIdx.x < NE) counts[threadIdx.x] = 0;
}

// ------------- router: wave per token, also emits xb = bf16(x) -------------
__global__ __launch_bounds__(256) void k_router(const float* __restrict__ x,
                                                const float* __restrict__ gw,
                                                unsigned short* __restrict__ xb,
                                                float* __restrict__ logits,
                                                int* __restrict__ sel,
                                                float* __restrict__ cw,
                                                int* __restrict__ counts) {
  int wid = threadIdx.x >> 6, lane = threadIdx.x & 63;
  int t = blockIdx.x * 4 + wid;
  const float4* xr = (const float4*)(x + (size_t)t * HID);
  float acc[NE];
#pragma unroll
  for (int e = 0; e < NE; e++) acc[e] = 0.f;
  for (int i = lane; i < HID / 4; i += 64) {
    float4 xv = xr[i];
    ushort4 o;
    o.x = f2bf(xv.x); o.y = f2bf(xv.y); o.z = f2bf(xv.z); o.w = f2bf(xv.w);
    *(ushort4*)(xb + (size_t)t * HID + i * 4) = o;
#pragma unroll
    for (int e = 0; e < NE; e++) {
      float4 gv = ((const float4*)(gw + (size_t)e * HID))[i];
      acc[e] += xv.x * gv.x + xv.y * gv.y + xv.z * gv.z + xv.w * gv.w;
    }
  }
#pragma unroll
  for (int e = 0; e < NE; e++)
    for (int off = 32; off; off >>= 1) acc[e] += __shfl_down(acc[e], off);
  if (lane == 0) {
    float mx = acc[0];
#pragma unroll
    for (int e = 1; e < NE; e++) mx = fmaxf(mx, acc[e]);
    float p[NE];
#pragma unroll
    for (int e = 0; e < NE; e++) p[e] = expf(acc[e] - mx);
    int i1 = 0; float b1 = p[0];
#pragma unroll
    for (int e = 1; e < NE; e++) if (p[e] > b1) { b1 = p[e]; i1 = e; }
    int i2 = -1; float b2 = -1.f;
#pragma unroll
    for (int e = 0; e < NE; e++) if (e != i1 && p[e] > b2) { b2 = p[e]; i2 = e; }
    float denom = b1 + b2;
#pragma unroll
    for (int e = 0; e < NE; e++) logits[(size_t)t * NE + e] = acc[e];
    sel[2 * t] = i1; sel[2 * t + 1] = i2;
    cw[2 * t] = b1 / denom; cw[2 * t + 1] = b2 / denom;
    atomicAdd(&counts[i1], 1);
    atomicAdd(&counts[i2], 1);
  }
}

__global__ void k_offsets(const int* __restrict__ counts, int* __restrict__ base,
                          int* __restrict__ cursor) {
  if (threadIdx.x == 0 && blockIdx.x == 0) {
    int acc = 0;
    for (int e = 0; e < NE; e++) { base[e] = acc; cursor[e] = acc; acc += counts[e]; }
    base[NE] = acc;
  }
}

__global__ __launch_bounds__(256) void k_scatter(const int* __restrict__ sel,
                                                 int* __restrict__ cursor,
                                                 int* __restrict__ tokc,
                                                 int* __restrict__ inv) {
  int t = blockIdx.x * blockDim.x + threadIdx.x;
  if (t >= T_TOK) return;
#pragma unroll
  for (int k = 0; k < 2; k++) {
    int e = sel[2 * t + k];
    int pos = atomicAdd(&cursor[e], 1);
    tokc[pos] = t;
    inv[2 * t + k] = pos;
  }
}

// XCD-aware remap (nwg % 8 == 0): XCD gets a contiguous chunk -> expert locality.
__device__ __forceinline__ int xcd_remap(int L, int nwg) {
  return (L & 7) * (nwg >> 3) + (L >> 3);
}

// ======== unified 256-row 2-phase MFMA GEMM, 8 waves (2M x 4N), wave 128x64 ========
// FUSED (GEMM1): B = w1[n0..n0+128) || w3[n0..n0+128); each wave owns 32 act-cols'
//                g AND u frags (A reused across both); epilogue writes silu(g)*u.
// !FUSED (GEMM2): plain 256x256 tile, B = w2 rows.
// 2-phase: STAGE(t+1 -> buf^1) BEFORE compute of buf; one __syncthreads per iter
// (compiler-emitted vmcnt(0)+lgkmcnt(0) is the drain). XOR chunk-swizzle: 0 conflicts.
template<bool FUSED, int KD, int ND>
__global__ __launch_bounds__(512, 2) void k_gemm(const u16* __restrict__ A,
                                                 const u16* __restrict__ W,
                                                 u16* __restrict__ Y,
                                                 const int* __restrict__ counts,
                                                 const int* __restrict__ base_,
                                                 const int* __restrict__ tokc) {
  int Wk = xcd_remap(blockIdx.x, 2048);
  int by = Wk & 7, bx = (Wk >> 3) & 31, e = Wk >> 8;

  int cnt = counts[e];
  int m0 = bx * 256;
  if (m0 >= cnt) return;
  constexpr int NCOL = FUSED ? 128 : 256;   // output cols per block
  int n0 = by * NCOL;
  int bs = base_[e];

  __shared__ u16 lds[2][2 * 256 * 64];   // per buf: A[256][64] then B[256][64]
  __shared__ int s_row[256];

  int tid = threadIdx.x;
  if (FUSED) {
    if (tid < 256) {
      int sl = m0 + tid;
      s_row[tid] = tokc[bs + (sl < cnt ? sl : 0)];
    }
    __syncthreads();
  }

  int wave = tid >> 6, lane = tid & 63;
  int l3 = lane >> 3, l7 = lane & 7;
  int cs = l7 ^ l3;  // pre-swizzled 16B chunk of global source

  const u16* wb = W + (size_t)e * (FUSED ? (2 * FFNW) * HID : HID * FFNW);

  size_t aoff[4], boff[4];
  unsigned abase[4], bbase[4];
#pragma unroll
  for (int i = 0; i < 4; i++) {
    int lrow = i * 64 + wave * 8;
    int r = lrow + l3;
    if (FUSED) {
      aoff[i] = (size_t)s_row[r] * KD + (size_t)cs * 8;
    } else {
      int sl = m0 + r;
      aoff[i] = (size_t)(bs + (sl < cnt ? sl : 0)) * KD + (size_t)cs * 8;
    }
    abase[i] = (unsigned)(lrow * 64);
    int growb = FUSED ? (r < 128 ? n0 + r : FFNW + n0 + (r - 128)) : (n0 + r);
    boff[i] = (size_t)growb * KD + (size_t)cs * 8;
    bbase[i] = (unsigned)(256 * 64 + lrow * 64);
  }

  f32x4 acc[8][4];
#pragma unroll
  for (int mi = 0; mi < 8; mi++)
#pragma unroll
    for (int ni = 0; ni < 4; ni++) acc[mi][ni] = (f32x4)(0.f);

  int wm = wave >> 2, wn = wave & 3;   // 2M x 4N
  int arow = wm * 128;
  int frow = lane & 15, fk = lane >> 4;

  constexpr int NT = KD / 64;

  auto STAGE = [&](int buf, int t) {
    size_t ko = (size_t)t * 64;
#pragma unroll
    for (int i = 0; i < 4; i++) {
      GLOAD16(A + aoff[i] + ko, &lds[buf][abase[i]]);
      GLOAD16(wb + boff[i] + ko, &lds[buf][bbase[i]]);
    }
  };

  STAGE(0, 0);
  __syncthreads();   // vmcnt(0): buf0 landed

  int cur = 0;
  for (int t = 0; t < NT; ++t) {
    if (t + 1 < NT) STAGE(cur ^ 1, t + 1);   // overlaps with compute below
    const char* sb = (const char*)lds[cur];
#pragma unroll
    for (int kk = 0; kk < 2; kk++) {
      int sw = ((fk + kk * 4) ^ (frow & 7)) << 4;  // swizzled 16B chunk (per-lane)
      short8 af[8], bf[4];
#pragma unroll
      for (int mi = 0; mi < 8; mi++)
        af[mi] = *(const short8*)(sb + (arow + mi * 16 + frow) * 128 + sw);
#pragma unroll
      for (int n = 0; n < 4; n++) {
        int rb = FUSED ? ((n >> 1) * 128 + wn * 32 + (n & 1) * 16 + frow)
                       : (wn * 64 + n * 16 + frow);
        bf[n] = *(const short8*)(sb + 256 * 128 + rb * 128 + sw);
      }
#pragma unroll
      for (int mi = 0; mi < 8; mi++)
#pragma unroll
        for (int n = 0; n < 4; n++)
          acc[mi][n] = __builtin_amdgcn_mfma_f32_16x16x32_bf16(af[mi], bf[n], acc[mi][n], 0, 0, 0);
    }
    __syncthreads();   // drain: next buf landed, all reads done
    cur ^= 1;
  }

  // epilogue: C/D col=lane&15, row=(lane>>4)*4+r
#pragma unroll
  for (int mi = 0; mi < 8; mi++) {
#pragma unroll
    for (int r = 0; r < 4; r++) {
      int row = arow + mi * 16 + fk * 4 + r;
      int sl = m0 + row;
      if (sl < cnt) {
        if (FUSED) {
          u16* yr = Y + (size_t)(bs + sl) * ND + n0 + wn * 32 + frow;
#pragma unroll
          for (int j = 0; j < 2; j++) {
            float g = acc[mi][j][r];
            float u = acc[mi][j + 2][r];
            float sv = g / (1.f + expf(-g));
            yr[j * 16] = f2bf(sv * u);
          }
        } else {
          u16* yr = Y + (size_t)(bs + sl) * ND + n0 + wn * 64 + frow;
#pragma unroll
          for (int n = 0; n < 4; n++) yr[n * 16] = f2bf(acc[mi][n][r]);
        }
      }
    }
  }
}

// ---------------- combine: out[t] = c0*y[p0] + c1*y[p1] ----------------
__global__ __launch_bounds__(256) void k_combine(const unsigned short* __restrict__ y,
                                                 const int* __restrict__ inv,
                                                 const float* __restrict__ cw,
                                                 float* __restrict__ out) {
  long i = (long)blockIdx.x * 256 + threadIdx.x;
  int t = (int)(i >> 8);
  int c = (int)(i & 255);
  int p0 = inv[2 * t], p1 = inv[2 * t + 1];
  float c0 = cw[2 * t], c1 = cw[2 * t + 1];
  short8 y0 = *(const short8*)(y + (size_t)p0 * HID + c * 8);
  short8 y1 = *(const short8*)(y + (size_t)p1 * HID + c * 8);
  float4 o0, o1;
  o0.x = c0 * bf2f((unsigned short)y0[0]) + c1 * bf2f((unsigned short)y1[0]);
  o0.y = c0 * bf2f((unsigned short)y0[1]) + c1 * bf2f((unsigned short)y1[1]);
  o0.z = c0 * bf2f((unsigned short)y0[2]) + c1 * bf2f((unsigned short)y1[2]);
  o0.w = c0 * bf2f((unsigned short)y0[3]) + c1 * bf2f((unsigned short)y1[3]);
  o1.x = c0 * bf2f((unsigned short)y0[4]) + c1 * bf2f((unsigned short)y1[4]);
  o1.y = c0 * bf2f((unsigned short)y0[5]) + c1 * bf2f((unsigned short)y1[5]);
  o1.z = c0 * bf2f((unsigned short)y0[6]) + c1 * bf2f((unsigned short)y1[6]);
  o1.w = c0 * bf2f((unsigned short)y0[7]) + c1 * bf2f((unsigned short)y1[7]);
  float4* op = (float4*)(out + (size_t)t * HID + c * 8);
  op[0] = o0;
  op[1] = o1;
}

extern "C" void kernel_launch(void* const* d_in, const int* in_sizes, int n_in,
                              void* d_out, int out_size, void* d_ws, size_t ws_size,
                              hipStream_t stream) {
  const float* x   = (const float*)d_in[0];
  const float* gw  = (const float*)d_in[1];
  const float* w13 = (const float*)d_in[2];
  const float* w2  = (const float*)d_in[3];
  float* out = (float*)d_out;
  float* logits = out + (size_t)T_TOK * HID;

  uint8_t* p = (uint8_t*)d_ws;
  unsigned short* xb   = (unsigned short*)p; p += (size_t)T_TOK * HID * 2;
  unsigned short* w13b = (unsigned short*)p; p += (size_t)NE * 2 * FFNW * HID * 2;
  unsigned short* w2b  = (unsigned short*)p; p += (size_t)NE * HID * FFNW * 2;
  unsigned short* act  = (unsigned short*)p; p += (size_t)NPAIR * FFNW * 2;
  unsigned short* y    = (unsigned short*)p; p += (size_t)NPAIR * HID * 2;
  int* sel  = (int*)p;   p += (size_t)T_TOK * 2 * 4;
  float* cw = (float*)p; p += (size_t)T_TOK * 2 * 4;
  int* tokc = (int*)p;   p += (size_t)NPAIR * 4;
  int* inv  = (int*)p;   p += (size_t)NPAIR * 4;
  int* counts = (int*)p; p += 256;
  int* cursor = (int*)p; p += 256;
  int* base   = (int*)p; p += 256;
  if ((size_t)(p - (uint8_t*)d_ws) > ws_size) return;

  k_cast<<<2048, 256, 0, stream>>>(w13, w13b, (long)NE * 2 * FFNW * HID / 8);
  k_cast<<<2048, 256, 0, stream>>>(w2, w2b, (long)NE * HID * FFNW / 8);
  k_init<<<1, 64, 0, stream>>>(counts);
  k_router<<<T_TOK / 4, 256, 0, stream>>>(x, gw, xb, logits, sel, cw, counts);
  k_offsets<<<1, 1, 0, stream>>>(counts, base, cursor);
  k_scatter<<<T_TOK / 256, 256, 0, stream>>>(sel, cursor, tokc, inv);

  // GEMM1 + fused SwiGLU: act[pair][F]  (256 rows x 128 act-cols per block)
  k_gemm<true, HID, FFNW><<<2048, 512, 0, stream>>>(xb, w13b, act, counts, base, tokc);
  // GEMM2: y[pair][H]  (256 x 256 per block)
  k_gemm<false, FFNW, HID><<<2048, 512, 0, stream>>>(act, w2b, y, counts, base, tokc);
  // combine into out
  k_combine<<<(int)((long)T_TOK * HID / 8 / 256), 256, 0, stream>>>(y, inv, cw, out);
}